// Round 8
// baseline (637.126 us; speedup 1.0000x reference)
//
#include <hip/hip_runtime.h>
#include <hip/hip_bf16.h>
#include <math.h>

using bf16 = __hip_bfloat16;
using bf162 = __hip_bfloat162;
typedef __attribute__((ext_vector_type(8))) short frag_ab;   // 8 bf16 (4 VGPRs)
typedef __attribute__((ext_vector_type(4))) float frag_cd;   // 4 fp32 acc
typedef __attribute__((ext_vector_type(16))) float f32x16;   // 32x32 MFMA acc

typedef const __attribute__((address_space(1))) void* gptr_t;
typedef __attribute__((address_space(3))) void* lptr_t;

#define NUM_HEADS 16
#define KV_GROUPS 4
#define SEQ 2048
#define BATCH 4
#define FDIM 2048
#define DH 128
#define NQKV 3072   // H*DH + G*DH + G*DH

// ---------------- fp32 -> bf16 convert (vec4) ----------------
__global__ __launch_bounds__(256) void cvt_f32_bf16(const float* __restrict__ in,
                                                    bf16* __restrict__ out, int n4) {
  int i = blockIdx.x * 256 + threadIdx.x;
  if (i >= n4) return;
  float4 v = ((const float4*)in)[i];
  bf162 a; a.x = __float2bfloat16(v.x); a.y = __float2bfloat16(v.y);
  bf162 b; b.x = __float2bfloat16(v.z); b.y = __float2bfloat16(v.w);
  ((bf162*)out)[2 * i]     = a;
  ((bf162*)out)[2 * i + 1] = b;
}

// ---------------- transpose + cvt: src fp32 [R][C] -> dst bf16 [C][R] ----------------
__global__ __launch_bounds__(256) void transpose_cvt(const float* __restrict__ src,
                                                     bf16* __restrict__ dst,
                                                     int R, int C) {
  __shared__ float tile[64][65];
  const int ct = blockIdx.x, rt = blockIdx.y;
  const int t = threadIdx.x;
  const int c4 = (t & 15) * 4, r0 = t >> 4;
#pragma unroll
  for (int p = 0; p < 4; p++) {
    int r = r0 + p * 16;
    float4 v = *(const float4*)(src + (size_t)(rt * 64 + r) * C + ct * 64 + c4);
    tile[r][c4] = v.x; tile[r][c4 + 1] = v.y; tile[r][c4 + 2] = v.z; tile[r][c4 + 3] = v.w;
  }
  __syncthreads();
  const int cr = t >> 2, k0 = (t & 3) * 16;
  union { int4 v[2]; bf16 h[16]; } u;
#pragma unroll
  for (int i = 0; i < 16; i++) u.h[i] = __float2bfloat16(tile[k0 + i][cr]);
  bf16* d = dst + (size_t)(ct * 64 + cr) * R + rt * 64 + k0;
  *(int4*)d = u.v[0];
  *(int4*)(d + 8) = u.v[1];
}

// ---------------- bf16 transpose: Vb[bg][SEQ][DH] -> VT[bg][DH][SEQ] ----------------
__global__ __launch_bounds__(256) void transpose_v(const bf16* __restrict__ Vb,
                                                   bf16* __restrict__ VT) {
  __shared__ bf16 tile[64][136];
  const int kt = blockIdx.x, bg = blockIdx.y;
  const int t = threadIdx.x;
  const int key = t >> 2, c4 = t & 3;
  const bf16* src = Vb + ((size_t)bg * SEQ + kt * 64 + key) * DH + c4 * 32;
#pragma unroll
  for (int p = 0; p < 4; p++) {
    union { int4 v; bf16 hh[8]; } u;
    u.v = *(const int4*)(src + p * 8);
#pragma unroll
    for (int j = 0; j < 8; j++) tile[key][c4 * 32 + p * 8 + j] = u.hh[j];
  }
  __syncthreads();
  const int dt = t >> 3, kb8 = t & 7;
#pragma unroll
  for (int p2 = 0; p2 < 4; p2++) {
    int d = p2 * 32 + dt;
    union { int4 v; bf16 hh[8]; } u;
#pragma unroll
    for (int j = 0; j < 8; j++) u.hh[j] = tile[kb8 * 8 + j][d];
    *(int4*)(VT + ((size_t)bg * DH + d) * SEQ + kt * 64 + kb8 * 8) = u.v;
  }
}

// ---------------- m97-style bf16 MFMA GEMM (unchanged) ----------------
template <int OUTBF>
__global__ __launch_bounds__(256) void gemm128(const bf16* __restrict__ A,
                                               const bf16* __restrict__ BT,
                                               void* __restrict__ Cout,
                                               const float* __restrict__ bias,
                                               int M, int N, int K) {
  __shared__ bf16 a_lds[128 * 32];
  __shared__ bf16 b_lds[128 * 32];
  const int tid = threadIdx.x;
  const int wave = tid >> 6, lane = tid & 63;
  const int quad = lane >> 4, l16 = lane & 15;
  const int m0 = blockIdx.x * 128, n0 = blockIdx.y * 128;
  const int wm = (wave & 1) * 64, wn = (wave >> 1) * 64;

  frag_cd acc[4][4];
#pragma unroll
  for (int mt = 0; mt < 4; mt++)
#pragma unroll
    for (int nt = 0; nt < 4; nt++) acc[mt][nt] = (frag_cd){0.f, 0.f, 0.f, 0.f};

  const int seg0 = wave * 64 + lane;
  const int seg1 = (4 + wave) * 64 + lane;
  const bf16* aP0 = A  + (size_t)(m0 + (seg0 >> 2)) * K + (seg0 & 3) * 8;
  const bf16* aP1 = A  + (size_t)(m0 + (seg1 >> 2)) * K + (seg1 & 3) * 8;
  const bf16* bP0 = BT + (size_t)(n0 + (seg0 >> 2)) * K + (seg0 & 3) * 8;
  const bf16* bP1 = BT + (size_t)(n0 + (seg1 >> 2)) * K + (seg1 & 3) * 8;
  bf16* aL0 = &a_lds[(size_t)wave * 64 * 8];
  bf16* aL1 = &a_lds[(size_t)(4 + wave) * 64 * 8];
  bf16* bL0 = &b_lds[(size_t)wave * 64 * 8];
  bf16* bL1 = &b_lds[(size_t)(4 + wave) * 64 * 8];

  for (int k0 = 0; k0 < K; k0 += 32) {
    __syncthreads();
    __builtin_amdgcn_global_load_lds((gptr_t)(aP0 + k0), (lptr_t)aL0, 16, 0, 0);
    __builtin_amdgcn_global_load_lds((gptr_t)(aP1 + k0), (lptr_t)aL1, 16, 0, 0);
    __builtin_amdgcn_global_load_lds((gptr_t)(bP0 + k0), (lptr_t)bL0, 16, 0, 0);
    __builtin_amdgcn_global_load_lds((gptr_t)(bP1 + k0), (lptr_t)bL1, 16, 0, 0);
    __syncthreads();

    frag_ab af[4], bfr[4];
#pragma unroll
    for (int mt = 0; mt < 4; mt++)
      af[mt] = *(const frag_ab*)&a_lds[(wm + mt * 16 + l16) * 32 + quad * 8];
#pragma unroll
    for (int nt = 0; nt < 4; nt++)
      bfr[nt] = *(const frag_ab*)&b_lds[(wn + nt * 16 + l16) * 32 + quad * 8];
#pragma unroll
    for (int mt = 0; mt < 4; mt++)
#pragma unroll
      for (int nt = 0; nt < 4; nt++)
        acc[mt][nt] = __builtin_amdgcn_mfma_f32_16x16x32_bf16(af[mt], bfr[nt], acc[mt][nt], 0, 0, 0);
  }

#pragma unroll
  for (int mt = 0; mt < 4; mt++) {
#pragma unroll
    for (int nt = 0; nt < 4; nt++) {
#pragma unroll
      for (int r = 0; r < 4; r++) {
        int row = m0 + wm + mt * 16 + quad * 4 + r;
        int col = n0 + wn + nt * 16 + l16;
        float v = acc[mt][nt][r];
        if (bias) v += bias[col];
        if (OUTBF) ((bf16*)Cout)[(size_t)row * N + col] = __float2bfloat16(v);
        else       ((float*)Cout)[(size_t)row * N + col] = v;
      }
    }
  }
}

// ---------------- bias + RoPE + scale + scatter ----------------
__global__ __launch_bounds__(256) void rope_scatter(const bf16* __restrict__ qkv,
                                                    const float* __restrict__ bq,
                                                    const float* __restrict__ bk,
                                                    const float* __restrict__ bv,
                                                    bf16* __restrict__ Q,
                                                    bf16* __restrict__ K,
                                                    bf16* __restrict__ V) {
  int hrg  = blockIdx.x * 4 + (threadIdx.x >> 6);
  int lane = threadIdx.x & 63;
  int hr  = hrg % 24;
  int row = hrg / 24;
  int b = row >> 11, s = row & 2047;
  int kind, idx;
  if (hr < 16)      { kind = 0; idx = hr; }
  else if (hr < 20) { kind = 1; idx = hr - 16; }
  else              { kind = 2; idx = hr - 20; }
  int colbase = (kind == 0) ? idx * 128 : (kind == 1 ? 2048 + idx * 128 : 2560 + idx * 128);
  const bf16* src = qkv + (size_t)row * NQKV + colbase;
  bf162 xv = *(const bf162*)(src + 2 * lane);
  float a  = __bfloat162float(xv.x);
  float bb = __bfloat162float(xv.y);
  const float* bias = (kind == 0) ? bq : (kind == 1 ? bk : bv);
  a  += bias[idx * 128 + 2 * lane];
  bb += bias[idx * 128 + 2 * lane + 1];
  if (kind != 2 && lane < 32) {
    float freq = powf(10000.f, -(float)lane / 32.f);
    float ang  = (float)s * freq;
    float c = cosf(ang), sn = sinf(ang);
    float na = a * c - bb * sn;
    float nb = bb * c + a * sn;
    a = na; bb = nb;
  }
  if (kind == 0) { a *= 0.08838834764831845f; bb *= 0.08838834764831845f; }
  bf16* dst;
  if (kind == 0)      dst = Q + ((size_t)((b * NUM_HEADS + idx) * SEQ + s)) * DH;
  else if (kind == 1) dst = K + ((size_t)((b * KV_GROUPS + idx) * SEQ + s)) * DH;
  else                dst = V + ((size_t)((b * KV_GROUPS + idx) * SEQ + s)) * DH;
  bf162 ov; ov.x = __float2bfloat16(a); ov.y = __float2bfloat16(bb);
  *(bf162*)(dst + 2 * lane) = ov;
}

// pack two f32 -> dword of 2 bf16 (lo = first arg). Union pun (bf162 is not
// trivially copyable). Compiler fuses the converts into a pack (m240).
__device__ __forceinline__ unsigned pkbf2(float lo, float hi) {
  union { bf16 h[2]; unsigned u; } cv;
  cv.h[0] = __float2bfloat16(lo);
  cv.h[1] = __float2bfloat16(hi);
  return cv.u;
}

// ---------------- MFMA flash attention, 32x32x16 swapped-QK^T ----------------
// Round-8: PERSISTENT BALANCED GRID. 512 blocks, block w processes work items
// {w, 1023-w}. Item i -> (bh = i&63, t = 15-(i>>6)); pair's K-iteration total
// is (2*t1+2)+(2*(15-t1)+2) = 34 for EVERY block -> zero straggler tail,
// steady 2 blocks/CU occupancy (round-7 counters: avg occupancy 11% vs 25%
// possible = tail-dominated). Inner loop unchanged (dbuf 2x32KB, T3-minimum).
__global__ __launch_bounds__(256) void attn_mfma(const bf16* __restrict__ Q,
                                                 const bf16* __restrict__ K,
                                                 const bf16* __restrict__ VT,
                                                 bf16* __restrict__ O) {
  __shared__ __align__(16) char smem[65536];   // buf c: K at c*32768, V^T at +16384

  const int tid  = threadIdx.x;
  const int wave = tid >> 6, lane = tid & 63;
  const int l31  = lane & 31, hi = lane >> 5;

  for (int item = 0; item < 2; item++) {
    const int i  = (item == 0) ? (int)blockIdx.x : 1023 - (int)blockIdx.x;
    const int bh = i & 63;
    const int t  = 15 - (i >> 6);
    const int h = bh & 15, b = bh >> 4;
    const int grp = h >> 2;
    const int q0 = t * 128;
    const int qa = q0 + wave * 32 + l31;      // this lane's absolute q row

    const bf16* Qp     = Q  + ((size_t)(b * NUM_HEADS + h) * SEQ + qa) * DH;
    const bf16* Kbase  = K  + (size_t)(b * KV_GROUPS + grp) * SEQ * DH;
    const bf16* VTbase = VT + (size_t)(b * KV_GROUPS + grp) * DH * SEQ;

    // Q held as B-frags: B[k=dim][col=q]; lane (l31,hi) -> Q[qa][dc*16+hi*8+j]
    frag_ab qf[8];
#pragma unroll
    for (int dc = 0; dc < 8; dc++)
      qf[dc] = *(const frag_ab*)(Qp + dc * 16 + hi * 8);

    // O^T accumulators: D[row=d][col=q=lane&31], 4 tiles of 32 d
    f32x16 oacc[4];
#pragma unroll
    for (int dbi = 0; dbi < 4; dbi++)
#pragma unroll
      for (int r = 0; r < 16; r++) oacc[dbi][r] = 0.f;
    float m_r = -1e30f, l_r = 0.f;

    const int nkb    = 2 * t + 2;             // keys [0, q0+128)
    const int kblast = 2 * t + (wave >> 1);   // wave's last (diagonal) block

    // stage K + V^T tile kb into buffer c (each wave loads its 1/4)
    auto stage = [&](int c, int kb) {
      bf16* kl = (bf16*)(smem + c * 32768);
      bf16* vl = (bf16*)(smem + c * 32768 + 16384);
      const bf16* Kt = Kbase + (size_t)kb * 64 * DH;
#pragma unroll
      for (int ii = 0; ii < 4; ii++) {
        int seg = (ii * 4 + wave) * 64 + lane;          // [0,1024)
        int row = seg >> 4, blk = seg & 15;
        __builtin_amdgcn_global_load_lds(
            (gptr_t)(Kt + (size_t)row * DH + ((blk ^ (row & 15)) << 3)),
            (lptr_t)(kl + seg * 8), 16, 0, 0);
      }
#pragma unroll
      for (int ii = 0; ii < 4; ii++) {
        int seg = (ii * 4 + wave) * 64 + lane;          // [0,1024)
        int d = seg >> 3, blk = seg & 7;
        __builtin_amdgcn_global_load_lds(
            (gptr_t)(VTbase + (size_t)d * SEQ + kb * 64 + ((blk ^ (d & 7)) << 3)),
            (lptr_t)(vl + seg * 8), 16, 0, 0);
      }
    };

    __syncthreads();       // protect prev item's epilogue LDS reads from staging
    stage(0, 0);
    __syncthreads();                           // buf0 ready
    int cur = 0;

    for (int kb = 0; kb < nkb; kb++) {
      if (kb + 1 < nkb) stage(cur ^ 1, kb + 1);   // issue next tile (overlaps compute)

      if (kb <= kblast) {                      // wave-uniform guard
        const bf16* k_lds  = (const bf16*)(smem + cur * 32768);
        const bf16* vt_lds = (const bf16*)(smem + cur * 32768 + 16384);

        // --- QK^T (swapped): sacc[kc] = S^T chunk, col = q ---
        f32x16 sacc[2];
#pragma unroll
        for (int c = 0; c < 2; c++)
#pragma unroll
          for (int r = 0; r < 16; r++) sacc[c][r] = 0.f;
#pragma unroll
        for (int kc = 0; kc < 2; kc++) {
          const int krow = kc * 32 + l31;
          const int sw = (krow & 15) << 4;
#pragma unroll
          for (int dc = 0; dc < 8; dc++) {
            frag_ab kf = *(const frag_ab*)&k_lds[krow * 128 + (((dc * 32 + hi * 16) ^ sw) >> 1)];
            sacc[kc] = __builtin_amdgcn_mfma_f32_32x32x16_bf16(kf, qf[dc], sacc[kc], 0, 0, 0);
          }
        }
        // --- causal mask (only on the wave's diagonal block) ---
        if (kb == kblast) {
          const int kb64 = kb * 64 + 4 * hi;
#pragma unroll
          for (int c = 0; c < 2; c++)
#pragma unroll
            for (int r = 0; r < 16; r++) {
              int k = kb64 + c * 32 + (r & 3) + 8 * (r >> 2);
              if (k > qa) sacc[c][r] = -1e30f;
            }
        }
        // --- online softmax, lane-local; defer-max (T13, THR=8) ---
        float mx = -1e30f;
#pragma unroll
        for (int c = 0; c < 2; c++)
#pragma unroll
          for (int r = 0; r < 16; r++) mx = fmaxf(mx, sacc[c][r]);
        mx = fmaxf(mx, __shfl_xor(mx, 32));
        if (__any(mx > m_r + 8.f)) {
          float mnew = fmaxf(m_r, mx);
          float alpha = __expf(m_r - mnew);
          l_r *= alpha;
#pragma unroll
          for (int dbi = 0; dbi < 4; dbi++)
#pragma unroll
            for (int r = 0; r < 16; r++) oacc[dbi][r] *= alpha;
          m_r = mnew;
        }
        float ps = 0.f;
#pragma unroll
        for (int c = 0; c < 2; c++)
#pragma unroll
          for (int r = 0; r < 16; r++) {
            float p = __expf(sacc[c][r] - m_r);
            sacc[c][r] = p;
            ps += p;
          }
        ps += __shfl_xor(ps, 32);
        l_r += ps;

        // --- P -> bf16 B-frags in-register (cvt + shfl_xor + select) ---
        // reg r of sacc[c] holds key c*32 + (r&3) + 8*(r>>2) + 4*hi (q = l31).
        frag_ab pa[4];
#pragma unroll
        for (int c = 0; c < 2; c++)
#pragma unroll
          for (int ks = 0; ks < 2; ks++) {
            unsigned z0 = pkbf2(sacc[c][8 * ks + 0], sacc[c][8 * ks + 1]); // keys (0,1)+4hi
            unsigned z1 = pkbf2(sacc[c][8 * ks + 2], sacc[c][8 * ks + 3]); // keys (2,3)+4hi
            unsigned z2 = pkbf2(sacc[c][8 * ks + 4], sacc[c][8 * ks + 5]); // keys (8,9)+4hi
            unsigned z3 = pkbf2(sacc[c][8 * ks + 6], sacc[c][8 * ks + 7]); // keys (10,11)+4hi
            unsigned s0 = (unsigned)__shfl_xor((int)z0, 32);
            unsigned s1 = (unsigned)__shfl_xor((int)z1, 32);
            unsigned s2 = (unsigned)__shfl_xor((int)z2, 32);
            unsigned s3 = (unsigned)__shfl_xor((int)z3, 32);
            union { unsigned u[4]; frag_ab f; } w;
            w.u[0] = hi ? s2 : z0;   // keys (8,9)   / (0,1)
            w.u[1] = hi ? s3 : z1;   // keys (10,11) / (2,3)
            w.u[2] = hi ? z2 : s0;   // keys (12,13) / (4,5)
            w.u[3] = hi ? z3 : s1;   // keys (14,15) / (6,7)
            pa[c * 2 + ks] = w.f;
          }
        // --- PV: O^T += V^T * P^T ---
#pragma unroll
        for (int dbi = 0; dbi < 4; dbi++) {
          const int d = dbi * 32 + l31;
          const int sw = (d & 7) << 4;
#pragma unroll
          for (int ks = 0; ks < 4; ks++) {
            frag_ab vf = *(const frag_ab*)&vt_lds[d * 64 + (((ks * 32 + hi * 16) ^ sw) >> 1)];
            oacc[dbi] = __builtin_amdgcn_mfma_f32_32x32x16_bf16(vf, pa[ks], oacc[dbi], 0, 0, 0);
          }
        }
      }

      __syncthreads();   // drains vmcnt(0): next buffer staged AND this buffer's reads done
      cur ^= 1;
    }

    // --- epilogue: O^T -> LDS (swizzled) -> coalesced global store ---
    const float invl = 1.f / l_r;
    const int qrow = wave * 32 + l31;
#pragma unroll
    for (int dbi = 0; dbi < 4; dbi++)
#pragma unroll
      for (int ii = 0; ii < 8; ii++) {
        int dd = ((2 * ii) & 3) + 8 * (ii >> 1) + 4 * hi;   // even; pair covers dd,dd+1
        unsigned pv = pkbf2(oacc[dbi][2 * ii] * invl, oacc[dbi][2 * ii + 1] * invl);
        int colb = (dbi * 32 + dd) * 2;
        *(unsigned*)(smem + qrow * 256 + (colb ^ ((qrow & 15) << 4))) = pv;
      }
    __syncthreads();
    const int rr = tid >> 1, hf = tid & 1;
    bf16* Op = O + (size_t)(b * SEQ + q0 + rr) * FDIM + h * DH + hf * 64;
#pragma unroll
    for (int ii = 0; ii < 8; ii++) {
      int colb = hf * 128 + ii * 16;
      int4 v = *(const int4*)(smem + rr * 256 + (colb ^ ((rr & 15) << 4)));
      *(int4*)(Op + ii * 8) = v;
    }
  }
}

extern "C" void kernel_launch(void* const* d_in, const int* in_sizes, int n_in,
                              void* d_out, int out_size, void* d_ws, size_t ws_size,
                              hipStream_t stream) {
  const float* x  = (const float*)d_in[0];
  const float* wq = (const float*)d_in[1];
  const float* bq = (const float*)d_in[2];
  const float* wk = (const float*)d_in[3];
  const float* bk = (const float*)d_in[4];
  const float* wv = (const float*)d_in[5];
  const float* bv = (const float*)d_in[6];
  const float* wo = (const float*)d_in[7];
  const float* bo = (const float*)d_in[8];
  float* out = (float*)d_out;

  char* ws = (char*)d_ws;
  size_t off = 0;
  auto alloc = [&](size_t bytes) {
    void* p = ws + off;
    off += (bytes + 255) & ~(size_t)255;
    return p;
  };
  const size_t MS = (size_t)BATCH * SEQ;          // 8192
  bf16* Xb    = (bf16*)alloc(MS * FDIM * 2);
  bf16* WqkvT = (bf16*)alloc((size_t)NQKV * FDIM * 2);
  bf16* WoT   = (bf16*)alloc((size_t)FDIM * FDIM * 2);
  bf16* QKV   = (bf16*)alloc(MS * NQKV * 2);
  bf16* Qb    = (bf16*)alloc((size_t)BATCH * NUM_HEADS * SEQ * DH * 2);
  bf16* Kb    = (bf16*)alloc((size_t)BATCH * KV_GROUPS * SEQ * DH * 2);
  bf16* Vb    = (bf16*)alloc((size_t)BATCH * KV_GROUPS * SEQ * DH * 2);
  bf16* VTb   = (bf16*)alloc((size_t)BATCH * KV_GROUPS * DH * SEQ * 2);
  bf16* Ob    = (bf16*)alloc(MS * FDIM * 2);

  int n4x = (int)(MS * FDIM / 4);
  cvt_f32_bf16<<<(n4x + 255) / 256, 256, 0, stream>>>(x, Xb, n4x);

  transpose_cvt<<<dim3(2048 / 64, 2048 / 64), 256, 0, stream>>>(wq, WqkvT, 2048, 2048);
  transpose_cvt<<<dim3(512 / 64, 2048 / 64), 256, 0, stream>>>(wk, WqkvT + (size_t)2048 * 2048, 2048, 512);
  transpose_cvt<<<dim3(512 / 64, 2048 / 64), 256, 0, stream>>>(wv, WqkvT + (size_t)2560 * 2048, 2048, 512);
  transpose_cvt<<<dim3(2048 / 64, 2048 / 64), 256, 0, stream>>>(wo, WoT, 2048, 2048);

  dim3 g1(MS / 128, NQKV / 128);
  gemm128<1><<<g1, 256, 0, stream>>>(Xb, WqkvT, QKV, nullptr, (int)MS, NQKV, FDIM);

  rope_scatter<<<(int)(MS * 24 / 4), 256, 0, stream>>>(QKV, bq, bk, bv, Qb, Kb, Vb);

  transpose_v<<<dim3(SEQ / 64, BATCH * KV_GROUPS), 256, 0, stream>>>(Vb, VTb);

  attn_mfma<<<dim3(512), 256, 0, stream>>>(Qb, Kb, VTb, Ob);

  dim3 g2(MS / 128, FDIM / 128);
  gemm128<0><<<g2, 256, 0, stream>>>(Ob, WoT, out, bo, (int)MS, FDIM, FDIM);
}

// Round 9
// 560.833 us; speedup vs baseline: 1.1360x; 1.1360x over previous
//
#include <hip/hip_runtime.h>
#include <hip/hip_bf16.h>
#include <math.h>

using bf16 = __hip_bfloat16;
using bf162 = __hip_bfloat162;
typedef __attribute__((ext_vector_type(8))) short frag_ab;   // 8 bf16 (4 VGPRs)
typedef __attribute__((ext_vector_type(4))) float frag_cd;   // 4 fp32 acc
typedef __attribute__((ext_vector_type(16))) float f32x16;   // 32x32 MFMA acc

typedef const __attribute__((address_space(1))) void* gptr_t;
typedef __attribute__((address_space(3))) void* lptr_t;

#define NUM_HEADS 16
#define KV_GROUPS 4
#define SEQ 2048
#define BATCH 4
#define FDIM 2048
#define DH 128
#define NQKV 3072   // H*DH + G*DH + G*DH

// ---------------- fp32 -> bf16 convert (vec4) ----------------
__global__ __launch_bounds__(256) void cvt_f32_bf16(const float* __restrict__ in,
                                                    bf16* __restrict__ out, int n4) {
  int i = blockIdx.x * 256 + threadIdx.x;
  if (i >= n4) return;
  float4 v = ((const float4*)in)[i];
  bf162 a; a.x = __float2bfloat16(v.x); a.y = __float2bfloat16(v.y);
  bf162 b; b.x = __float2bfloat16(v.z); b.y = __float2bfloat16(v.w);
  ((bf162*)out)[2 * i]     = a;
  ((bf162*)out)[2 * i + 1] = b;
}

// ---------------- transpose + cvt: src fp32 [R][C] -> dst bf16 [C][R] ----------------
__global__ __launch_bounds__(256) void transpose_cvt(const float* __restrict__ src,
                                                     bf16* __restrict__ dst,
                                                     int R, int C) {
  __shared__ float tile[64][65];
  const int ct = blockIdx.x, rt = blockIdx.y;
  const int t = threadIdx.x;
  const int c4 = (t & 15) * 4, r0 = t >> 4;
#pragma unroll
  for (int p = 0; p < 4; p++) {
    int r = r0 + p * 16;
    float4 v = *(const float4*)(src + (size_t)(rt * 64 + r) * C + ct * 64 + c4);
    tile[r][c4] = v.x; tile[r][c4 + 1] = v.y; tile[r][c4 + 2] = v.z; tile[r][c4 + 3] = v.w;
  }
  __syncthreads();
  const int cr = t >> 2, k0 = (t & 3) * 16;
  union { int4 v[2]; bf16 h[16]; } u;
#pragma unroll
  for (int i = 0; i < 16; i++) u.h[i] = __float2bfloat16(tile[k0 + i][cr]);
  bf16* d = dst + (size_t)(ct * 64 + cr) * R + rt * 64 + k0;
  *(int4*)d = u.v[0];
  *(int4*)(d + 8) = u.v[1];
}

// ---------------- bf16 transpose: Vb[bg][SEQ][DH] -> VT[bg][DH][SEQ] ----------------
__global__ __launch_bounds__(256) void transpose_v(const bf16* __restrict__ Vb,
                                                   bf16* __restrict__ VT) {
  __shared__ bf16 tile[64][136];
  const int kt = blockIdx.x, bg = blockIdx.y;
  const int t = threadIdx.x;
  const int key = t >> 2, c4 = t & 3;
  const bf16* src = Vb + ((size_t)bg * SEQ + kt * 64 + key) * DH + c4 * 32;
#pragma unroll
  for (int p = 0; p < 4; p++) {
    union { int4 v; bf16 hh[8]; } u;
    u.v = *(const int4*)(src + p * 8);
#pragma unroll
    for (int j = 0; j < 8; j++) tile[key][c4 * 32 + p * 8 + j] = u.hh[j];
  }
  __syncthreads();
  const int dt = t >> 3, kb8 = t & 7;
#pragma unroll
  for (int p2 = 0; p2 < 4; p2++) {
    int d = p2 * 32 + dt;
    union { int4 v; bf16 hh[8]; } u;
#pragma unroll
    for (int j = 0; j < 8; j++) u.hh[j] = tile[kb8 * 8 + j][d];
    *(int4*)(VT + ((size_t)bg * DH + d) * SEQ + kt * 64 + kb8 * 8) = u.v;
  }
}

// ---------------- 256x256 counted-vmcnt ring GEMM: C = A[M,K] * BT[N,K]^T ----------------
// 512 threads = 8 waves (2 M x 4 N), per-wave output 128x64, BK=32.
// LDS: ring of 4 K-tile buffers x (A 16KB + B 16KB) = 128 KiB.
// Per K-tile: ONE counted s_waitcnt vmcnt + ONE raw s_barrier -- no vmcnt(0)
// drain in the main loop (T4). Prefetch depth 3 (stage kt+3 each iter).
// 16B-block XOR swizzle cblk ^= (row>>1)&3 on BOTH stage-source and ds_read
// (rule #21) -> 2 lanes/bank-group on the b128 fragment reads (conflict-free).
template <int OUTBF>
__global__ __launch_bounds__(512, 2) void gemm256(const bf16* __restrict__ A,
                                                  const bf16* __restrict__ BT,
                                                  void* __restrict__ Cout,
                                                  const float* __restrict__ bias,
                                                  int M, int N, int K) {
  __shared__ __align__(16) char lds[131072];   // buf b at b*32768: A 16KB | B 16KB
  const int tid = threadIdx.x;
  const int lane = tid & 63;
  const int wave = tid >> 6;
  const int quad = lane >> 4, l16 = lane & 15;
  const int wm = wave >> 2, wn = wave & 3;         // 2 x 4 wave grid
  const int m0 = blockIdx.x * 256, n0 = blockIdx.y * 256;
  const int NKT = K >> 5;                          // K-tiles of 32

  frag_cd acc[8][4];
#pragma unroll
  for (int mt = 0; mt < 8; mt++)
#pragma unroll
    for (int nt = 0; nt < 4; nt++) acc[mt][nt] = (frag_cd){0.f, 0.f, 0.f, 0.f};

  // stage K-tile kt into ring buffer (kt&3): 4 x global_load_lds(16B)/thread
  auto stage = [&](int kt) {
    char* base = lds + (size_t)(kt & 3) * 32768;
    const size_t kcol = (size_t)kt * 32;
#pragma unroll
    for (int i = 0; i < 2; i++) {
      int db = (i * 512 + tid) * 16;
      int row = db >> 6;
      int cblk = ((db >> 4) & 3) ^ ((row >> 1) & 3);   // inverse swizzle on source
      __builtin_amdgcn_global_load_lds(
          (gptr_t)(A + (size_t)(m0 + row) * K + kcol + cblk * 8),
          (lptr_t)(base + db), 16, 0, 0);
    }
#pragma unroll
    for (int i = 0; i < 2; i++) {
      int db = (i * 512 + tid) * 16;
      int row = db >> 6;
      int cblk = ((db >> 4) & 3) ^ ((row >> 1) & 3);
      __builtin_amdgcn_global_load_lds(
          (gptr_t)(BT + (size_t)(n0 + row) * K + kcol + cblk * 8),
          (lptr_t)(base + 16384 + db), 16, 0, 0);
    }
  };

  const int asw = ((l16 >> 1) & 3) << 4;             // read-side 16B-block swizzle

  // one K-tile of compute (call with the right vmcnt already issued)
  auto ktile = [&](int kt) {
    asm volatile("" ::: "memory");
    __builtin_amdgcn_s_barrier();                    // raw barrier: no drain
    asm volatile("" ::: "memory");
    if (kt + 3 < NKT) stage(kt + 3);                 // targets buf[(kt-1)&3], freed by barrier

    const char* base = lds + (size_t)(kt & 3) * 32768;
    const char* aB = base;
    const char* bB = base + 16384;
    frag_ab bfr[4];
#pragma unroll
    for (int nt = 0; nt < 4; nt++) {
      int row = wn * 64 + nt * 16 + l16;
      bfr[nt] = *(const frag_ab*)(bB + row * 64 + ((quad * 16) ^ asw));
    }
    __builtin_amdgcn_s_setprio(1);
#pragma unroll
    for (int mt = 0; mt < 8; mt++) {
      int row = wm * 128 + mt * 16 + l16;
      frag_ab af = *(const frag_ab*)(aB + row * 64 + ((quad * 16) ^ asw));
#pragma unroll
      for (int nt = 0; nt < 4; nt++)
        acc[mt][nt] = __builtin_amdgcn_mfma_f32_16x16x32_bf16(af, bfr[nt], acc[mt][nt], 0, 0, 0);
    }
    __builtin_amdgcn_s_setprio(0);
  };

  // prologue: 3 K-tiles in flight
  stage(0); stage(1); stage(2);

  for (int kt = 0; kt < NKT - 2; kt++) {
    asm volatile("s_waitcnt vmcnt(8)" ::: "memory");   // kt's 4 chunks landed (own thread)
    ktile(kt);
  }
  asm volatile("s_waitcnt vmcnt(4)" ::: "memory");
  ktile(NKT - 2);
  asm volatile("s_waitcnt vmcnt(0)" ::: "memory");     // final drain (once)
  ktile(NKT - 1);

  // epilogue: C write (col = l16, row = quad*4 + r within each 16x16 frag)
#pragma unroll
  for (int mt = 0; mt < 8; mt++) {
#pragma unroll
    for (int nt = 0; nt < 4; nt++) {
#pragma unroll
      for (int r = 0; r < 4; r++) {
        int row = m0 + wm * 128 + mt * 16 + quad * 4 + r;
        int col = n0 + wn * 64 + nt * 16 + l16;
        float v = acc[mt][nt][r];
        if (bias) v += bias[col];
        if (OUTBF) ((bf16*)Cout)[(size_t)row * N + col] = __float2bfloat16(v);
        else       ((float*)Cout)[(size_t)row * N + col] = v;
      }
    }
  }
}

// ---------------- bias + RoPE + scale + scatter ----------------
__global__ __launch_bounds__(256) void rope_scatter(const bf16* __restrict__ qkv,
                                                    const float* __restrict__ bq,
                                                    const float* __restrict__ bk,
                                                    const float* __restrict__ bv,
                                                    bf16* __restrict__ Q,
                                                    bf16* __restrict__ K,
                                                    bf16* __restrict__ V) {
  int hrg  = blockIdx.x * 4 + (threadIdx.x >> 6);
  int lane = threadIdx.x & 63;
  int hr  = hrg % 24;
  int row = hrg / 24;
  int b = row >> 11, s = row & 2047;
  int kind, idx;
  if (hr < 16)      { kind = 0; idx = hr; }
  else if (hr < 20) { kind = 1; idx = hr - 16; }
  else              { kind = 2; idx = hr - 20; }
  int colbase = (kind == 0) ? idx * 128 : (kind == 1 ? 2048 + idx * 128 : 2560 + idx * 128);
  const bf16* src = qkv + (size_t)row * NQKV + colbase;
  bf162 xv = *(const bf162*)(src + 2 * lane);
  float a  = __bfloat162float(xv.x);
  float bb = __bfloat162float(xv.y);
  const float* bias = (kind == 0) ? bq : (kind == 1 ? bk : bv);
  a  += bias[idx * 128 + 2 * lane];
  bb += bias[idx * 128 + 2 * lane + 1];
  if (kind != 2 && lane < 32) {
    float freq = powf(10000.f, -(float)lane / 32.f);
    float ang  = (float)s * freq;
    float c = cosf(ang), sn = sinf(ang);
    float na = a * c - bb * sn;
    float nb = bb * c + a * sn;
    a = na; bb = nb;
  }
  if (kind == 0) { a *= 0.08838834764831845f; bb *= 0.08838834764831845f; }
  bf16* dst;
  if (kind == 0)      dst = Q + ((size_t)((b * NUM_HEADS + idx) * SEQ + s)) * DH;
  else if (kind == 1) dst = K + ((size_t)((b * KV_GROUPS + idx) * SEQ + s)) * DH;
  else                dst = V + ((size_t)((b * KV_GROUPS + idx) * SEQ + s)) * DH;
  bf162 ov; ov.x = __float2bfloat16(a); ov.y = __float2bfloat16(bb);
  *(bf162*)(dst + 2 * lane) = ov;
}

// pack two f32 -> dword of 2 bf16 (lo = first arg). Union pun (bf162 is not
// trivially copyable). Compiler fuses the converts into a pack (m240).
__device__ __forceinline__ unsigned pkbf2(float lo, float hi) {
  union { bf16 h[2]; unsigned u; } cv;
  cv.h[0] = __float2bfloat16(lo);
  cv.h[1] = __float2bfloat16(hi);
  return cv.u;
}

// ---------------- MFMA flash attention, 32x32x16 swapped-QK^T ----------------
// (round-7 version: dbuf 2x32KB, T3-minimum schedule; round-8 persistent grid
// reverted -- it was neutral-to-worse, imbalance theory falsified)
__global__ __launch_bounds__(256) void attn_mfma(const bf16* __restrict__ Q,
                                                 const bf16* __restrict__ K,
                                                 const bf16* __restrict__ VT,
                                                 bf16* __restrict__ O) {
  __shared__ __align__(16) char smem[65536];   // buf c: K at c*32768, V^T at +16384

  const int tid  = threadIdx.x;
  const int wave = tid >> 6, lane = tid & 63;
  const int l31  = lane & 31, hi = lane >> 5;

  const int bh = blockIdx.x & 63;           // tile-major dispatch: big tiles first
  const int t  = 15 - (blockIdx.x >> 6);
  const int h = bh & 15, b = bh >> 4;
  const int grp = h >> 2;
  const int q0 = t * 128;
  const int qa = q0 + wave * 32 + l31;      // this lane's absolute q row

  const bf16* Qp     = Q  + ((size_t)(b * NUM_HEADS + h) * SEQ + qa) * DH;
  const bf16* Kbase  = K  + (size_t)(b * KV_GROUPS + grp) * SEQ * DH;
  const bf16* VTbase = VT + (size_t)(b * KV_GROUPS + grp) * DH * SEQ;

  frag_ab qf[8];
#pragma unroll
  for (int dc = 0; dc < 8; dc++)
    qf[dc] = *(const frag_ab*)(Qp + dc * 16 + hi * 8);

  f32x16 oacc[4];
#pragma unroll
  for (int dbi = 0; dbi < 4; dbi++)
#pragma unroll
    for (int r = 0; r < 16; r++) oacc[dbi][r] = 0.f;
  float m_r = -1e30f, l_r = 0.f;

  const int nkb    = 2 * t + 2;             // keys [0, q0+128)
  const int kblast = 2 * t + (wave >> 1);   // wave's last (diagonal) block

  auto stage = [&](int c, int kb) {
    bf16* kl = (bf16*)(smem + c * 32768);
    bf16* vl = (bf16*)(smem + c * 32768 + 16384);
    const bf16* Kt = Kbase + (size_t)kb * 64 * DH;
#pragma unroll
    for (int i = 0; i < 4; i++) {
      int seg = (i * 4 + wave) * 64 + lane;          // [0,1024)
      int row = seg >> 4, blk = seg & 15;
      __builtin_amdgcn_global_load_lds(
          (gptr_t)(Kt + (size_t)row * DH + ((blk ^ (row & 15)) << 3)),
          (lptr_t)(kl + seg * 8), 16, 0, 0);
    }
#pragma unroll
    for (int i = 0; i < 4; i++) {
      int seg = (i * 4 + wave) * 64 + lane;          // [0,1024)
      int d = seg >> 3, blk = seg & 7;
      __builtin_amdgcn_global_load_lds(
          (gptr_t)(VTbase + (size_t)d * SEQ + kb * 64 + ((blk ^ (d & 7)) << 3)),
          (lptr_t)(vl + seg * 8), 16, 0, 0);
    }
  };

  stage(0, 0);
  __syncthreads();                           // buf0 ready
  int cur = 0;

  for (int kb = 0; kb < nkb; kb++) {
    if (kb + 1 < nkb) stage(cur ^ 1, kb + 1);   // issue next tile (overlaps compute)

    if (kb <= kblast) {                      // wave-uniform guard
      const bf16* k_lds  = (const bf16*)(smem + cur * 32768);
      const bf16* vt_lds = (const bf16*)(smem + cur * 32768 + 16384);

      f32x16 sacc[2];
#pragma unroll
      for (int c = 0; c < 2; c++)
#pragma unroll
        for (int r = 0; r < 16; r++) sacc[c][r] = 0.f;
#pragma unroll
      for (int kc = 0; kc < 2; kc++) {
        const int krow = kc * 32 + l31;
        const int sw = (krow & 15) << 4;
#pragma unroll
        for (int dc = 0; dc < 8; dc++) {
          frag_ab kf = *(const frag_ab*)&k_lds[krow * 128 + (((dc * 32 + hi * 16) ^ sw) >> 1)];
          sacc[kc] = __builtin_amdgcn_mfma_f32_32x32x16_bf16(kf, qf[dc], sacc[kc], 0, 0, 0);
        }
      }
      if (kb == kblast) {
        const int kb64 = kb * 64 + 4 * hi;
#pragma unroll
        for (int c = 0; c < 2; c++)
#pragma unroll
          for (int r = 0; r < 16; r++) {
            int k = kb64 + c * 32 + (r & 3) + 8 * (r >> 2);
            if (k > qa) sacc[c][r] = -1e30f;
          }
      }
      float mx = -1e30f;
#pragma unroll
      for (int c = 0; c < 2; c++)
#pragma unroll
        for (int r = 0; r < 16; r++) mx = fmaxf(mx, sacc[c][r]);
      mx = fmaxf(mx, __shfl_xor(mx, 32));
      if (__any(mx > m_r + 8.f)) {
        float mnew = fmaxf(m_r, mx);
        float alpha = __expf(m_r - mnew);
        l_r *= alpha;
#pragma unroll
        for (int dbi = 0; dbi < 4; dbi++)
#pragma unroll
          for (int r = 0; r < 16; r++) oacc[dbi][r] *= alpha;
        m_r = mnew;
      }
      float ps = 0.f;
#pragma unroll
      for (int c = 0; c < 2; c++)
#pragma unroll
        for (int r = 0; r < 16; r++) {
          float p = __expf(sacc[c][r] - m_r);
          sacc[c][r] = p;
          ps += p;
        }
      ps += __shfl_xor(ps, 32);
      l_r += ps;

      frag_ab pa[4];
#pragma unroll
      for (int c = 0; c < 2; c++)
#pragma unroll
        for (int ks = 0; ks < 2; ks++) {
          unsigned z0 = pkbf2(sacc[c][8 * ks + 0], sacc[c][8 * ks + 1]);
          unsigned z1 = pkbf2(sacc[c][8 * ks + 2], sacc[c][8 * ks + 3]);
          unsigned z2 = pkbf2(sacc[c][8 * ks + 4], sacc[c][8 * ks + 5]);
          unsigned z3 = pkbf2(sacc[c][8 * ks + 6], sacc[c][8 * ks + 7]);
          unsigned s0 = (unsigned)__shfl_xor((int)z0, 32);
          unsigned s1 = (unsigned)__shfl_xor((int)z1, 32);
          unsigned s2 = (unsigned)__shfl_xor((int)z2, 32);
          unsigned s3 = (unsigned)__shfl_xor((int)z3, 32);
          union { unsigned u[4]; frag_ab f; } w;
          w.u[0] = hi ? s2 : z0;
          w.u[1] = hi ? s3 : z1;
          w.u[2] = hi ? z2 : s0;
          w.u[3] = hi ? z3 : s1;
          pa[c * 2 + ks] = w.f;
        }
#pragma unroll
      for (int dbi = 0; dbi < 4; dbi++) {
        const int d = dbi * 32 + l31;
        const int sw = (d & 7) << 4;
#pragma unroll
        for (int ks = 0; ks < 4; ks++) {
          frag_ab vf = *(const frag_ab*)&vt_lds[d * 64 + (((ks * 32 + hi * 16) ^ sw) >> 1)];
          oacc[dbi] = __builtin_amdgcn_mfma_f32_32x32x16_bf16(vf, pa[ks], oacc[dbi], 0, 0, 0);
        }
      }
    }

    __syncthreads();   // drains vmcnt(0): next buffer staged AND this buffer's reads done
    cur ^= 1;
  }

  const float invl = 1.f / l_r;
  const int qrow = wave * 32 + l31;
#pragma unroll
  for (int dbi = 0; dbi < 4; dbi++)
#pragma unroll
    for (int i = 0; i < 8; i++) {
      int dd = ((2 * i) & 3) + 8 * (i >> 1) + 4 * hi;
      unsigned pv = pkbf2(oacc[dbi][2 * i] * invl, oacc[dbi][2 * i + 1] * invl);
      int colb = (dbi * 32 + dd) * 2;
      *(unsigned*)(smem + qrow * 256 + (colb ^ ((qrow & 15) << 4))) = pv;
    }
  __syncthreads();
  const int rr = tid >> 1, hf = tid & 1;
  bf16* Op = O + (size_t)(b * SEQ + q0 + rr) * FDIM + h * DH + hf * 64;
#pragma unroll
  for (int i = 0; i < 8; i++) {
    int colb = hf * 128 + i * 16;
    int4 v = *(const int4*)(smem + rr * 256 + (colb ^ ((rr & 15) << 4)));
    *(int4*)(Op + i * 8) = v;
  }
}

extern "C" void kernel_launch(void* const* d_in, const int* in_sizes, int n_in,
                              void* d_out, int out_size, void* d_ws, size_t ws_size,
                              hipStream_t stream) {
  const float* x  = (const float*)d_in[0];
  const float* wq = (const float*)d_in[1];
  const float* bq = (const float*)d_in[2];
  const float* wk = (const float*)d_in[3];
  const float* bk = (const float*)d_in[4];
  const float* wv = (const float*)d_in[5];
  const float* bv = (const float*)d_in[6];
  const float* wo = (const float*)d_in[7];
  const float* bo = (const float*)d_in[8];
  float* out = (float*)d_out;

  char* ws = (char*)d_ws;
  size_t off = 0;
  auto alloc = [&](size_t bytes) {
    void* p = ws + off;
    off += (bytes + 255) & ~(size_t)255;
    return p;
  };
  const size_t MS = (size_t)BATCH * SEQ;          // 8192
  bf16* Xb    = (bf16*)alloc(MS * FDIM * 2);
  bf16* WqkvT = (bf16*)alloc((size_t)NQKV * FDIM * 2);
  bf16* WoT   = (bf16*)alloc((size_t)FDIM * FDIM * 2);
  bf16* QKV   = (bf16*)alloc(MS * NQKV * 2);
  bf16* Qb    = (bf16*)alloc((size_t)BATCH * NUM_HEADS * SEQ * DH * 2);
  bf16* Kb    = (bf16*)alloc((size_t)BATCH * KV_GROUPS * SEQ * DH * 2);
  bf16* Vb    = (bf16*)alloc((size_t)BATCH * KV_GROUPS * SEQ * DH * 2);
  bf16* VTb   = (bf16*)alloc((size_t)BATCH * KV_GROUPS * DH * SEQ * 2);
  bf16* Ob    = (bf16*)alloc(MS * FDIM * 2);

  int n4x = (int)(MS * FDIM / 4);
  cvt_f32_bf16<<<(n4x + 255) / 256, 256, 0, stream>>>(x, Xb, n4x);

  transpose_cvt<<<dim3(2048 / 64, 2048 / 64), 256, 0, stream>>>(wq, WqkvT, 2048, 2048);
  transpose_cvt<<<dim3(512 / 64, 2048 / 64), 256, 0, stream>>>(wk, WqkvT + (size_t)2048 * 2048, 2048, 512);
  transpose_cvt<<<dim3(512 / 64, 2048 / 64), 256, 0, stream>>>(wv, WqkvT + (size_t)2560 * 2048, 2048, 512);
  transpose_cvt<<<dim3(2048 / 64, 2048 / 64), 256, 0, stream>>>(wo, WoT, 2048, 2048);

  dim3 g1(8192 / 256, NQKV / 256);   // 32 x 12
  gemm256<1><<<g1, 512, 0, stream>>>(Xb, WqkvT, QKV, nullptr, (int)MS, NQKV, FDIM);

  rope_scatter<<<(int)(MS * 24 / 4), 256, 0, stream>>>(QKV, bq, bk, bv, Qb, Kb, Vb);

  transpose_v<<<dim3(SEQ / 64, BATCH * KV_GROUPS), 256, 0, stream>>>(Vb, VTb);

  attn_mfma<<<dim3(64 * 16), 256, 0, stream>>>(Qb, Kb, VTb, Ob);

  dim3 g2(8192 / 256, FDIM / 256);   // 32 x 8
  gemm256<0><<<g2, 512, 0, stream>>>(Ob, WoT, out, bo, (int)MS, FDIM, FDIM);
}